// Round 5
// baseline (732.840 us; speedup 1.0000x reference)
//
#include <hip/hip_runtime.h>

typedef unsigned short u16;
typedef unsigned int   u32;
typedef __attribute__((ext_vector_type(8))) short s16x8;
typedef __attribute__((ext_vector_type(4))) float f32x4;
typedef __attribute__((ext_vector_type(4))) u32   u32x4;
typedef __attribute__((ext_vector_type(4))) u16   u16x4;

#define NPIX 16641   /* 129*129 */
#define HP   131     /* padded spatial dim */

// ---- workspace layout (bytes) ----
// U   : [4][131][131][128] bf16  @ 0          (17,572,864)
// S1  : [2][131][131][512] bf16  @ 17572864   (35,145,728)
// Wt1 : [9][256][128] bf16       @ 52718592   (589,824)
// Wt2 : [9][256][512] bf16       @ 53308416   (2,359,296)
// out2: [2*16641][256] f32       @ 55667712   (34,080,768)  (relu'd)
// w3t : [256][49] f32            @ 89748480   (50,176)
// P   : [2][49][16641] f32       @ 89798656   (6,523,272)
// total 96,321,928 B

__device__ __forceinline__ u16 f2bf(float f) {
    u32 b = __builtin_bit_cast(u32, f);
    return (u16)((b + 0x7fffu + ((b >> 16) & 1u)) >> 16);
}

// async global->LDS, 16B per lane; LDS dest wave-uniform base, lane l -> +16*l
__device__ __forceinline__ void async_cp16(const void* g, void* l) {
    __builtin_amdgcn_global_load_lds(
        (const __attribute__((address_space(1))) u32*)g,
        (__attribute__((address_space(3))) u32*)l, 16, 0, 0);
}

// zero only the 1-pixel pad ring of U (4 imgs, C=128) and S1 (2 imgs, C=512).
__global__ __launch_bounds__(256) void zero_border(u16* __restrict__ U,
                                                   u16* __restrict__ S1) {
    const int plane = blockIdx.y;           // 0..3: U, 4..5: S1
    const bool isU = plane < 4;
    const int C = isU ? 128 : 512;
    const int cpp = C / 8;
    int e = blockIdx.x * 256 + threadIdx.x;
    if (e >= 520 * cpp) return;
    int pix = e / cpp, ch = e - pix * cpp;
    int r, c;
    if (pix < 131)      { r = 0;   c = pix; }
    else if (pix < 262) { r = 130; c = pix - 131; }
    else { int j = pix - 262; r = 1 + (j >> 1); c = (j & 1) ? 130 : 0; }
    int img = isU ? plane : (plane - 4);
    u16* base = (isU ? U : S1) + ((long)(img * HP + r) * HP + c) * C + ch * 8;
    u32x4 z = {0u, 0u, 0u, 0u};
    *(u32x4*)base = z;
}

// transform weights: Wt[tap][co][ci] (bf16), w3t[c][t] (f32)
__global__ __launch_bounds__(256) void prep_weights(
        const float* __restrict__ wr, const float* __restrict__ w2,
        const float* __restrict__ w3,
        u16* __restrict__ Wt1, u16* __restrict__ Wt2, float* __restrict__ w3t) {
    int i = blockIdx.x * 256 + threadIdx.x;
    if (i < 294912) {
        int tap = i / 32768, r = i & 32767;
        int co = r >> 7, ci = r & 127;
        Wt1[i] = f2bf(wr[(co * 128 + ci) * 9 + tap]);
    } else if (i < 1474560) {
        int j = i - 294912;
        int tap = j / 131072, r = j & 131071;
        int co = r >> 9, ci = r & 511;
        Wt2[j] = f2bf(w2[(co * 512 + ci) * 9 + tap]);
    } else if (i < 1487104) {
        int j = i - 1474560;
        int c = j / 49, t = j - c * 49;
        w3t[j] = w3[t * 256 + c];
    }
}

// bilinear upsample 33x33 -> 129x129, write padded NHWC bf16
__global__ __launch_bounds__(256) void upsample(
        const float* __restrict__ cur, const float* __restrict__ key,
        u16* __restrict__ U) {
    __shared__ float rows[2][128][33];
    const int y = blockIdx.x;
    const int img = blockIdx.y;
    const int frame = img >> 1, bb = img & 1;
    const float* src = (frame ? key : cur) + (long)bb * 128 * 1089;
    const float scale = 33.0f / 129.0f;
    float syf = (y + 0.5f) * scale - 0.5f;
    int sy0 = (int)floorf(syf);
    float wy = syf - (float)sy0;
    int sy0c = sy0 < 0 ? 0 : sy0;
    int sy1c = (sy0 + 1 > 32) ? 32 : sy0 + 1;
    for (int e = threadIdx.x; e < 2 * 128 * 33; e += 256) {
        int rr = e / 4224;
        int rem = e - rr * 4224;
        int c = rem / 33, sx = rem - c * 33;
        rows[rr][c][sx] = src[((long)c * 33 + (rr ? sy1c : sy0c)) * 33 + sx];
    }
    __syncthreads();
    u16* dst = U + ((long)(img * HP + (y + 1)) * HP + 1) * 128;
    for (int e = threadIdx.x; e < 129 * 128; e += 256) {
        int x = e >> 7, c = e & 127;
        float sxf = (x + 0.5f) * scale - 0.5f;
        int sx0 = (int)floorf(sxf);
        float wx = sxf - (float)sx0;
        int sx0c = sx0 < 0 ? 0 : sx0;
        int sx1c = (sx0 + 1 > 32) ? 32 : sx0 + 1;
        float v0 = rows[0][c][sx0c] * (1.f - wx) + rows[0][c][sx1c] * wx;
        float v1 = rows[1][c][sx0c] * (1.f - wx) + rows[1][c][sx1c] * wx;
        dst[(long)x * 128 + c] = f2bf(v0 * (1.f - wy) + v1 * wy);
    }
}

// implicit-GEMM 3x3 conv via MFMA, 128x128 tile, BK=32.
// v3: K-steps ordered k-chunk-major (tap INNERMOST) so the same 3-row B slice
//     is revisited in 9 consecutive steps -> L1/L2 hits instead of HBM misses.
//     Weights (A) bypass LDS: loaded global->VGPR fragments with register
//     double-buffer (no intra-block A reuse; cross-block reuse lives in L2).
//     Only B goes through LDS (global_load_lds, conflict-free swizzle).
template<int CIN, int MODE, int NWORK>
__global__ __launch_bounds__(256) void conv_mfma(
        const u16* __restrict__ In, const u16* __restrict__ Wt,
        const float* __restrict__ bias,
        u16* __restrict__ OutBf, float* __restrict__ OutF) {
    constexpr int KC  = CIN / 32;
    constexpr int NS  = 9 * KC;
    constexpr int PER = (NWORK + 7) / 8;
    __shared__ u16 Bs[2][128 * 32];

    const int id = blockIdx.x;
    const int work = (id & 7) * PER + (id >> 3);
    if (work >= NWORK) return;
    const int m0  = (work & 1) * 128;
    const int xi  = (work >> 1) % 131;
    const int img = (work >> 1) / 131;
    const int p0  = xi * 128;

    const int t    = threadIdx.x;
    const int lane = t & 63;
    const int wave = t >> 6;
    const int wm = wave & 1, wn = wave >> 1;
    const int lm = lane & 15, lq = lane >> 4;
    // B reader chunk rotation (conflict-free, verified r4): chunk (lq+(lm>>1))&3
    const int koff = (((lq + (lm >> 1)) & 3) * 8);

    // ---- B staging map: wave w, issue j in {0,1} covers pixels
    //      [w*32 + j*16, +16) x 32ch; lane covers pixel l>>2, 16B slot l&3.
    //      Writer stores global chunk ((slot - (row>>1)) & 3) at slot.
    long ub[2];
    #pragma unroll
    for (int j = 0; j < 2; ++j) {
        int rowid = wave * 32 + j * 16 + (lane >> 2);
        int g = ((lane & 3) - (rowid >> 1)) & 3;
        int p = p0 + rowid; if (p > NPIX - 1) p = NPIX - 1;
        int y = p / 129, x = p - y * 129;
        ub[j] = ((long)(img * HP + y) * HP + x) * CIN + g * 8;
    }
    // ---- A fragment base: lane reads row m0+wm*64+mt*16+lm, k = kc + lq*8
    const long wa_base = (long)(m0 + wm * 64 + lm) * CIN + lq * 8;

    auto stageB = [&](int s, int buf) {
        const int kcq = s / 9;
        const int tap = s - kcq * 9;
        const int ky = tap / 3, kx = tap - ky * 3;
        const long toff = (long)(ky * HP + kx) * CIN + kcq * 32;
        char* Bw = (char*)&Bs[buf][0] + wave * 2048;
        async_cp16(In + ub[0] + toff, Bw);
        async_cp16(In + ub[1] + toff, Bw + 1024);
    };
    auto loadA = [&](int s, s16x8* fa) {
        const int kcq = s / 9;
        const int tap = s - kcq * 9;
        const u16* base = Wt + (long)tap * 256 * CIN + kcq * 32 + wa_base;
        #pragma unroll
        for (int mt = 0; mt < 4; ++mt)
            fa[mt] = *(const s16x8*)(base + (long)mt * 16 * CIN);
    };

    f32x4 acc[4][4];
    f32x4 zero = {0.f, 0.f, 0.f, 0.f};
    #pragma unroll
    for (int mt = 0; mt < 4; ++mt)
        #pragma unroll
        for (int nt = 0; nt < 4; ++nt) acc[mt][nt] = zero;

    s16x8 fa[2][4];
    loadA(0, fa[0]);
    stageB(0, 0);
    #pragma unroll 2
    for (int i = 0; i < NS; ++i) {
        const int buf = i & 1;
        __syncthreads();                  // Bs[buf] staged; Bs[buf^1] free
        if (i + 1 < NS) { loadA(i + 1, fa[buf ^ 1]); stageB(i + 1, buf ^ 1); }
        s16x8 fb[4];
        #pragma unroll
        for (int nt = 0; nt < 4; ++nt)
            fb[nt] = *(const s16x8*)&Bs[buf][(wn * 64 + nt * 16 + lm) * 32 + koff];
        #pragma unroll
        for (int mt = 0; mt < 4; ++mt)
            #pragma unroll
            for (int nt = 0; nt < 4; ++nt)
                acc[mt][nt] = __builtin_amdgcn_mfma_f32_16x16x32_bf16(
                    fa[buf][mt], fb[nt], acc[mt][nt], 0, 0, 0);
    }

    #pragma unroll
    for (int nt = 0; nt < 4; ++nt) {
        int p = p0 + wn * 64 + nt * 16 + lm;
        if (p > NPIX - 1) continue;
        long obase;
        if (MODE == 0) {
            int y = p / 129, x = p - y * 129;
            int bb = img & 1, frame = img >> 1;
            obase = ((long)(bb * HP + (y + 1)) * HP + (x + 1)) * 512 + frame * 256;
        } else {
            obase = ((long)img * NPIX + p) * 256;
        }
        #pragma unroll
        for (int mt = 0; mt < 4; ++mt) {
            int co = m0 + wm * 64 + mt * 16 + lq * 4;
            f32x4 bv = *(const f32x4*)(bias + co);
            float v0 = fmaxf(acc[mt][nt][0] + bv[0], 0.f);
            float v1 = fmaxf(acc[mt][nt][1] + bv[1], 0.f);
            float v2 = fmaxf(acc[mt][nt][2] + bv[2], 0.f);
            float v3 = fmaxf(acc[mt][nt][3] + bv[3], 0.f);
            if (MODE == 0) {
                u16x4 o = { f2bf(v0), f2bf(v1), f2bf(v2), f2bf(v3) };
                *(u16x4*)(OutBf + obase + co) = o;
            } else {
                f32x4 o = { v0, v1, v2, v3 };
                *(f32x4*)(OutF + obase + co) = o;
            }
        }
    }
}

// 1x1 conv (256->49) + softmax. 2 threads/pixel (128 ch each), LDS reduce.
__global__ __launch_bounds__(256) void conv3_softmax(
        const float* __restrict__ X, const float* __restrict__ W3t,
        const float* __restrict__ b3, float* __restrict__ P) {
    __shared__ float red[128][50];
    const int t = threadIdx.x;
    const int pl = t & 127, sub = t >> 7;
    const int idx = blockIdx.x * 128 + pl;
    const bool valid = idx < 2 * NPIX;
    float l[49];
    #pragma unroll
    for (int k = 0; k < 49; ++k) l[k] = 0.f;
    if (valid) {
        const f32x4* xr = (const f32x4*)(X + (long)idx * 256 + sub * 128);
        #pragma unroll 1
        for (int cb = 0; cb < 32; ++cb) {
            f32x4 xv = xr[cb];
            #pragma unroll
            for (int j = 0; j < 4; ++j) {
                float xc = fmaxf(xv[j], 0.f);
                const float* wrow = W3t + (sub * 128 + cb * 4 + j) * 49;
                #pragma unroll
                for (int k = 0; k < 49; ++k) l[k] = fmaf(wrow[k], xc, l[k]);
            }
        }
    }
    if (sub) {
        #pragma unroll
        for (int k = 0; k < 49; ++k) red[pl][k] = l[k];
    }
    __syncthreads();
    if (!sub && valid) {
        float m = 0.f;
        #pragma unroll
        for (int k = 0; k < 49; ++k) {
            l[k] = fmaxf(l[k] + red[pl][k] + b3[k], 0.f);
            m = fmaxf(m, l[k]);
        }
        float ssum = 0.f;
        #pragma unroll
        for (int k = 0; k < 49; ++k) { l[k] = __expf(l[k] - m); ssum += l[k]; }
        float inv = 1.f / ssum;
        int bb = idx / NPIX, pix = idx - bb * NPIX;
        float* Pp = P + (long)bb * 49 * NPIX + pix;
        #pragma unroll
        for (int k = 0; k < 49; ++k) Pp[(long)k * NPIX] = l[k] * inv;
    }
}

// spatially-variant 7x7 conv
__global__ __launch_bounds__(256) void svconv(
        const float* __restrict__ F, const float* __restrict__ P,
        float* __restrict__ Out) {
    int idx = blockIdx.x * 256 + threadIdx.x;
    if (idx >= 2 * 64 * NPIX) return;
    int pix = idx % NPIX;
    int r = idx / NPIX;
    int cg = (r & 63), bb = r >> 6;
    int y = pix / 129, x = pix - y * 129;
    float w[49];
    const float* Pp = P + (long)bb * 49 * NPIX + pix;
    #pragma unroll
    for (int t = 0; t < 49; ++t) w[t] = Pp[(long)t * NPIX];
    float acc0 = 0.f, acc1 = 0.f, acc2 = 0.f, acc3 = 0.f;
    const float* Fb = F + ((long)(bb * 256 + cg * 4)) * NPIX;
    #pragma unroll
    for (int ky = 0; ky < 7; ++ky) {
        unsigned uy = (unsigned)(y + ky - 3);
        #pragma unroll
        for (int kx = 0; kx < 7; ++kx) {
            unsigned ux = (unsigned)(x + kx - 3);
            if (uy < 129u && ux < 129u) {
                long o = (long)uy * 129 + ux;
                float wt = w[ky * 7 + kx];
                acc0 = fmaf(wt, Fb[o], acc0);
                acc1 = fmaf(wt, Fb[o + (long)NPIX], acc1);
                acc2 = fmaf(wt, Fb[o + 2L * NPIX], acc2);
                acc3 = fmaf(wt, Fb[o + 3L * NPIX], acc3);
            }
        }
    }
    float* Ob = Out + ((long)(bb * 256 + cg * 4)) * NPIX + pix;
    Ob[0] = acc0;
    Ob[(long)NPIX] = acc1;
    Ob[2L * NPIX] = acc2;
    Ob[3L * NPIX] = acc3;
}

extern "C" void kernel_launch(void* const* d_in, const int* in_sizes, int n_in,
                              void* d_out, int out_size, void* d_ws, size_t ws_size,
                              hipStream_t stream) {
    const float* cur      = (const float*)d_in[0];
    const float* key      = (const float*)d_in[1];
    const float* Fhigh    = (const float*)d_in[2];
    const float* w_reduce = (const float*)d_in[3];
    const float* b_reduce = (const float*)d_in[4];
    const float* w_conv2  = (const float*)d_in[5];
    const float* b_conv2  = (const float*)d_in[6];
    const float* w_conv3  = (const float*)d_in[7];
    const float* b_conv3  = (const float*)d_in[8];

    if (ws_size < 96321928UL) return;

    char* ws = (char*)d_ws;
    u16*   U    = (u16*)(ws + 0);
    u16*   S1   = (u16*)(ws + 17572864);
    u16*   Wt1  = (u16*)(ws + 52718592);
    u16*   Wt2  = (u16*)(ws + 53308416);
    float* out2 = (float*)(ws + 55667712);
    float* w3t  = (float*)(ws + 89748480);
    float* P    = (float*)(ws + 89798656);

    zero_border<<<dim3(130, 6), 256, 0, stream>>>(U, S1);
    prep_weights<<<5809, 256, 0, stream>>>(w_reduce, w_conv2, w_conv3, Wt1, Wt2, w3t);
    upsample<<<dim3(129, 4), 256, 0, stream>>>(cur, key, U);
    conv_mfma<128, 0, 1048><<<1048, 256, 0, stream>>>(U, Wt1, b_reduce, S1, nullptr);
    conv_mfma<512, 1, 524><<<528, 256, 0, stream>>>(S1, Wt2, b_conv2, nullptr, out2);
    conv3_softmax<<<261, 256, 0, stream>>>(out2, w3t, b_conv3, P);
    svconv<<<8321, 256, 0, stream>>>(Fhigh, P, (float*)d_out);
}

// Round 6
// 615.496 us; speedup vs baseline: 1.1907x; 1.1907x over previous
//
#include <hip/hip_runtime.h>

typedef unsigned short u16;
typedef unsigned int   u32;
typedef __attribute__((ext_vector_type(8))) short s16x8;
typedef __attribute__((ext_vector_type(4))) float f32x4;
typedef __attribute__((ext_vector_type(4))) u32   u32x4;
typedef __attribute__((ext_vector_type(4))) u16   u16x4;

#define NPIX 16641   /* 129*129 */
#define HP   131     /* padded spatial dim */

// ---- workspace layout (bytes) ----
// U   : [4][131][131][128] bf16  @ 0          (17,572,864)
// S1  : [2][131][131][512] bf16  @ 17572864   (35,145,728)
// Wt1 : [9][256][128] bf16       @ 52718592   (589,824)
// Wt2 : [9][256][512] bf16       @ 53308416   (2,359,296)
// out2: [2*16641][256] f32       @ 55667712   (34,080,768)  (relu'd)
// w3t : [256][49] f32            @ 89748480   (50,176)
// P   : [2][49][16641] f32       @ 89798656   (6,523,272)
// total 96,321,928 B

__device__ __forceinline__ u16 f2bf(float f) {
    u32 b = __builtin_bit_cast(u32, f);
    return (u16)((b + 0x7fffu + ((b >> 16) & 1u)) >> 16);
}

// async global->LDS, 16B per lane; LDS dest wave-uniform base, lane l -> +16*l
__device__ __forceinline__ void async_cp16(const void* g, void* l) {
    __builtin_amdgcn_global_load_lds(
        (const __attribute__((address_space(1))) u32*)g,
        (__attribute__((address_space(3))) u32*)l, 16, 0, 0);
}

// zero only the 1-pixel pad ring of U (4 imgs, C=128) and S1 (2 imgs, C=512).
__global__ __launch_bounds__(256) void zero_border(u16* __restrict__ U,
                                                   u16* __restrict__ S1) {
    const int plane = blockIdx.y;           // 0..3: U, 4..5: S1
    const bool isU = plane < 4;
    const int C = isU ? 128 : 512;
    const int cpp = C / 8;
    int e = blockIdx.x * 256 + threadIdx.x;
    if (e >= 520 * cpp) return;
    int pix = e / cpp, ch = e - pix * cpp;
    int r, c;
    if (pix < 131)      { r = 0;   c = pix; }
    else if (pix < 262) { r = 130; c = pix - 131; }
    else { int j = pix - 262; r = 1 + (j >> 1); c = (j & 1) ? 130 : 0; }
    int img = isU ? plane : (plane - 4);
    u16* base = (isU ? U : S1) + ((long)(img * HP + r) * HP + c) * C + ch * 8;
    u32x4 z = {0u, 0u, 0u, 0u};
    *(u32x4*)base = z;
}

// transform weights: Wt[tap][co][ci] (bf16), w3t[c][t] (f32)
__global__ __launch_bounds__(256) void prep_weights(
        const float* __restrict__ wr, const float* __restrict__ w2,
        const float* __restrict__ w3,
        u16* __restrict__ Wt1, u16* __restrict__ Wt2, float* __restrict__ w3t) {
    int i = blockIdx.x * 256 + threadIdx.x;
    if (i < 294912) {
        int tap = i / 32768, r = i & 32767;
        int co = r >> 7, ci = r & 127;
        Wt1[i] = f2bf(wr[(co * 128 + ci) * 9 + tap]);
    } else if (i < 1474560) {
        int j = i - 294912;
        int tap = j / 131072, r = j & 131071;
        int co = r >> 9, ci = r & 511;
        Wt2[j] = f2bf(w2[(co * 512 + ci) * 9 + tap]);
    } else if (i < 1487104) {
        int j = i - 1474560;
        int c = j / 49, t = j - c * 49;
        w3t[j] = w3[t * 256 + c];
    }
}

// bilinear upsample 33x33 -> 129x129, write padded NHWC bf16
__global__ __launch_bounds__(256) void upsample(
        const float* __restrict__ cur, const float* __restrict__ key,
        u16* __restrict__ U) {
    __shared__ float rows[2][128][33];
    const int y = blockIdx.x;
    const int img = blockIdx.y;
    const int frame = img >> 1, bb = img & 1;
    const float* src = (frame ? key : cur) + (long)bb * 128 * 1089;
    const float scale = 33.0f / 129.0f;
    float syf = (y + 0.5f) * scale - 0.5f;
    int sy0 = (int)floorf(syf);
    float wy = syf - (float)sy0;
    int sy0c = sy0 < 0 ? 0 : sy0;
    int sy1c = (sy0 + 1 > 32) ? 32 : sy0 + 1;
    for (int e = threadIdx.x; e < 2 * 128 * 33; e += 256) {
        int rr = e / 4224;
        int rem = e - rr * 4224;
        int c = rem / 33, sx = rem - c * 33;
        rows[rr][c][sx] = src[((long)c * 33 + (rr ? sy1c : sy0c)) * 33 + sx];
    }
    __syncthreads();
    u16* dst = U + ((long)(img * HP + (y + 1)) * HP + 1) * 128;
    for (int e = threadIdx.x; e < 129 * 128; e += 256) {
        int x = e >> 7, c = e & 127;
        float sxf = (x + 0.5f) * scale - 0.5f;
        int sx0 = (int)floorf(sxf);
        float wx = sxf - (float)sx0;
        int sx0c = sx0 < 0 ? 0 : sx0;
        int sx1c = (sx0 + 1 > 32) ? 32 : sx0 + 1;
        float v0 = rows[0][c][sx0c] * (1.f - wx) + rows[0][c][sx1c] * wx;
        float v1 = rows[1][c][sx0c] * (1.f - wx) + rows[1][c][sx1c] * wx;
        dst[(long)x * 128 + c] = f2bf(v0 * (1.f - wy) + v1 * wy);
    }
}

// implicit-GEMM 3x3 conv via MFMA, 128x128 tile, BK=32 (r4 structure).
// v4: 4-buffer LDS pipeline, prefetch depth 3, AITER-style fine-grained
// s_waitcnt vmcnt(N) + raw s_barrier (NEVER vmcnt(0) mid-loop) so prefetched
// global_load_lds stages stay in flight across barriers. Per wave each stage
// = 4 DMA ops; waiting vmcnt(8) leaves stages i+1,i+2 outstanding.
// LDS bank-conflict-free k-chunk rotation (verified r4: conflicts = 0).
template<int CIN, int MODE, int NWORK>
__global__ __launch_bounds__(256) void conv_mfma(
        const u16* __restrict__ In, const u16* __restrict__ Wt,
        const float* __restrict__ bias,
        u16* __restrict__ OutBf, float* __restrict__ OutF) {
    constexpr int KC  = CIN / 32;
    constexpr int NS  = 9 * KC;
    constexpr int PER = (NWORK + 7) / 8;
    __shared__ u16 As[4][128 * 32];   // 4 x 8 KB
    __shared__ u16 Bs[4][128 * 32];   // 4 x 8 KB  (64 KB total)

    const int id = blockIdx.x;
    const int work = (id & 7) * PER + (id >> 3);
    if (work >= NWORK) return;        // whole block exits -> raw s_barrier safe
    const int m0  = (work & 1) * 128;
    const int xi  = (work >> 1) % 131;
    const int img = (work >> 1) / 131;
    const int p0  = xi * 128;

    const int t    = threadIdx.x;
    const int srow = t >> 2;
    // swizzled global k-chunk for this staging lane (conflict-free, r4)
    const int scol = ((((t & 3) - (srow >> 1)) & 3) * 8);
    long ub[2];
    #pragma unroll
    for (int is = 0; is < 2; ++is) {
        int p = p0 + srow + is * 64; if (p > NPIX - 1) p = NPIX - 1;
        int y = p / 129, x = p - y * 129;
        ub[is] = ((long)(img * HP + y) * HP + x) * CIN + scol;
    }
    const long wb0 = (long)(m0 + srow) * CIN + scol;

    const int lane = t & 63;
    const int wave = t >> 6;
    const int wm = wave & 1, wn = wave >> 1;
    const int lm = lane & 15, lq = lane >> 4;
    const int koff = (((lq + (lm >> 1)) & 3) * 8);

    auto stage = [&](int s, int buf) {
        const int tap = s / KC;
        const int kc  = (s - tap * KC) * 32;
        const int ky = tap / 3, kx = tap - ky * 3;
        const long toff = (long)(ky * HP + kx) * CIN + kc;
        const u16* WtT = Wt + (long)tap * 256 * CIN + kc;
        char* Aw = (char*)&As[buf][0] + wave * 1024;
        char* Bw = (char*)&Bs[buf][0] + wave * 1024;
        async_cp16(WtT + wb0,             Aw);
        async_cp16(WtT + wb0 + 64L * CIN, Aw + 4096);
        async_cp16(In + ub[0] + toff,     Bw);
        async_cp16(In + ub[1] + toff,     Bw + 4096);
    };

    f32x4 acc[4][4];
    f32x4 zero = {0.f, 0.f, 0.f, 0.f};
    #pragma unroll
    for (int mt = 0; mt < 4; ++mt)
        #pragma unroll
        for (int nt = 0; nt < 4; ++nt) acc[mt][nt] = zero;

    stage(0, 0);
    stage(1, 1);
    stage(2, 2);                         // 12 DMA ops/wave in flight
    #pragma unroll 4
    for (int i = 0; i < NS; ++i) {
        const int buf = i & 3;
        // wait for stage i only; keep deeper prefetch in flight across barrier
        if (i < NS - 2)
            asm volatile("s_waitcnt vmcnt(8)\n\ts_barrier" ::: "memory");
        else if (i == NS - 2)
            asm volatile("s_waitcnt vmcnt(4)\n\ts_barrier" ::: "memory");
        else
            asm volatile("s_waitcnt vmcnt(0)\n\ts_barrier" ::: "memory");
        if (i + 3 < NS) stage(i + 3, (i + 3) & 3);
        s16x8 fa[4], fb[4];
        #pragma unroll
        for (int mt = 0; mt < 4; ++mt)
            fa[mt] = *(const s16x8*)&As[buf][(wm * 64 + mt * 16 + lm) * 32 + koff];
        #pragma unroll
        for (int nt = 0; nt < 4; ++nt)
            fb[nt] = *(const s16x8*)&Bs[buf][(wn * 64 + nt * 16 + lm) * 32 + koff];
        #pragma unroll
        for (int mt = 0; mt < 4; ++mt)
            #pragma unroll
            for (int nt = 0; nt < 4; ++nt)
                acc[mt][nt] = __builtin_amdgcn_mfma_f32_16x16x32_bf16(
                    fa[mt], fb[nt], acc[mt][nt], 0, 0, 0);
    }

    #pragma unroll
    for (int nt = 0; nt < 4; ++nt) {
        int p = p0 + wn * 64 + nt * 16 + lm;
        if (p > NPIX - 1) continue;
        long obase;
        if (MODE == 0) {
            int y = p / 129, x = p - y * 129;
            int bb = img & 1, frame = img >> 1;
            obase = ((long)(bb * HP + (y + 1)) * HP + (x + 1)) * 512 + frame * 256;
        } else {
            obase = ((long)img * NPIX + p) * 256;
        }
        #pragma unroll
        for (int mt = 0; mt < 4; ++mt) {
            int co = m0 + wm * 64 + mt * 16 + lq * 4;
            f32x4 bv = *(const f32x4*)(bias + co);
            float v0 = fmaxf(acc[mt][nt][0] + bv[0], 0.f);
            float v1 = fmaxf(acc[mt][nt][1] + bv[1], 0.f);
            float v2 = fmaxf(acc[mt][nt][2] + bv[2], 0.f);
            float v3 = fmaxf(acc[mt][nt][3] + bv[3], 0.f);
            if (MODE == 0) {
                u16x4 o = { f2bf(v0), f2bf(v1), f2bf(v2), f2bf(v3) };
                *(u16x4*)(OutBf + obase + co) = o;
            } else {
                f32x4 o = { v0, v1, v2, v3 };
                *(f32x4*)(OutF + obase + co) = o;
            }
        }
    }
}

// 1x1 conv (256->49) + softmax. 2 threads/pixel (128 ch each), LDS reduce.
__global__ __launch_bounds__(256) void conv3_softmax(
        const float* __restrict__ X, const float* __restrict__ W3t,
        const float* __restrict__ b3, float* __restrict__ P) {
    __shared__ float red[128][50];
    const int t = threadIdx.x;
    const int pl = t & 127, sub = t >> 7;
    const int idx = blockIdx.x * 128 + pl;
    const bool valid = idx < 2 * NPIX;
    float l[49];
    #pragma unroll
    for (int k = 0; k < 49; ++k) l[k] = 0.f;
    if (valid) {
        const f32x4* xr = (const f32x4*)(X + (long)idx * 256 + sub * 128);
        #pragma unroll 1
        for (int cb = 0; cb < 32; ++cb) {
            f32x4 xv = xr[cb];
            #pragma unroll
            for (int j = 0; j < 4; ++j) {
                float xc = fmaxf(xv[j], 0.f);
                const float* wrow = W3t + (sub * 128 + cb * 4 + j) * 49;
                #pragma unroll
                for (int k = 0; k < 49; ++k) l[k] = fmaf(wrow[k], xc, l[k]);
            }
        }
    }
    if (sub) {
        #pragma unroll
        for (int k = 0; k < 49; ++k) red[pl][k] = l[k];
    }
    __syncthreads();
    if (!sub && valid) {
        float m = 0.f;
        #pragma unroll
        for (int k = 0; k < 49; ++k) {
            l[k] = fmaxf(l[k] + red[pl][k] + b3[k], 0.f);
            m = fmaxf(m, l[k]);
        }
        float ssum = 0.f;
        #pragma unroll
        for (int k = 0; k < 49; ++k) { l[k] = __expf(l[k] - m); ssum += l[k]; }
        float inv = 1.f / ssum;
        int bb = idx / NPIX, pix = idx - bb * NPIX;
        float* Pp = P + (long)bb * 49 * NPIX + pix;
        #pragma unroll
        for (int k = 0; k < 49; ++k) Pp[(long)k * NPIX] = l[k] * inv;
    }
}

// spatially-variant 7x7 conv
__global__ __launch_bounds__(256) void svconv(
        const float* __restrict__ F, const float* __restrict__ P,
        float* __restrict__ Out) {
    int idx = blockIdx.x * 256 + threadIdx.x;
    if (idx >= 2 * 64 * NPIX) return;
    int pix = idx % NPIX;
    int r = idx / NPIX;
    int cg = (r & 63), bb = r >> 6;
    int y = pix / 129, x = pix - y * 129;
    float w[49];
    const float* Pp = P + (long)bb * 49 * NPIX + pix;
    #pragma unroll
    for (int t = 0; t < 49; ++t) w[t] = Pp[(long)t * NPIX];
    float acc0 = 0.f, acc1 = 0.f, acc2 = 0.f, acc3 = 0.f;
    const float* Fb = F + ((long)(bb * 256 + cg * 4)) * NPIX;
    #pragma unroll
    for (int ky = 0; ky < 7; ++ky) {
        unsigned uy = (unsigned)(y + ky - 3);
        #pragma unroll
        for (int kx = 0; kx < 7; ++kx) {
            unsigned ux = (unsigned)(x + kx - 3);
            if (uy < 129u && ux < 129u) {
                long o = (long)uy * 129 + ux;
                float wt = w[ky * 7 + kx];
                acc0 = fmaf(wt, Fb[o], acc0);
                acc1 = fmaf(wt, Fb[o + (long)NPIX], acc1);
                acc2 = fmaf(wt, Fb[o + 2L * NPIX], acc2);
                acc3 = fmaf(wt, Fb[o + 3L * NPIX], acc3);
            }
        }
    }
    float* Ob = Out + ((long)(bb * 256 + cg * 4)) * NPIX + pix;
    Ob[0] = acc0;
    Ob[(long)NPIX] = acc1;
    Ob[2L * NPIX] = acc2;
    Ob[3L * NPIX] = acc3;
}

extern "C" void kernel_launch(void* const* d_in, const int* in_sizes, int n_in,
                              void* d_out, int out_size, void* d_ws, size_t ws_size,
                              hipStream_t stream) {
    const float* cur      = (const float*)d_in[0];
    const float* key      = (const float*)d_in[1];
    const float* Fhigh    = (const float*)d_in[2];
    const float* w_reduce = (const float*)d_in[3];
    const float* b_reduce = (const float*)d_in[4];
    const float* w_conv2  = (const float*)d_in[5];
    const float* b_conv2  = (const float*)d_in[6];
    const float* w_conv3  = (const float*)d_in[7];
    const float* b_conv3  = (const float*)d_in[8];

    if (ws_size < 96321928UL) return;

    char* ws = (char*)d_ws;
    u16*   U    = (u16*)(ws + 0);
    u16*   S1   = (u16*)(ws + 17572864);
    u16*   Wt1  = (u16*)(ws + 52718592);
    u16*   Wt2  = (u16*)(ws + 53308416);
    float* out2 = (float*)(ws + 55667712);
    float* w3t  = (float*)(ws + 89748480);
    float* P    = (float*)(ws + 89798656);

    zero_border<<<dim3(130, 6), 256, 0, stream>>>(U, S1);
    prep_weights<<<5809, 256, 0, stream>>>(w_reduce, w_conv2, w_conv3, Wt1, Wt2, w3t);
    upsample<<<dim3(129, 4), 256, 0, stream>>>(cur, key, U);
    conv_mfma<128, 0, 1048><<<1048, 256, 0, stream>>>(U, Wt1, b_reduce, S1, nullptr);
    conv_mfma<512, 1, 524><<<528, 256, 0, stream>>>(S1, Wt2, b_conv2, nullptr, out2);
    conv3_softmax<<<261, 256, 0, stream>>>(out2, w3t, b_conv3, P);
    svconv<<<8321, 256, 0, stream>>>(Fhigh, P, (float*)d_out);
}

// Round 7
// 542.171 us; speedup vs baseline: 1.3517x; 1.1352x over previous
//
#include <hip/hip_runtime.h>

typedef unsigned short u16;
typedef unsigned int   u32;
typedef __attribute__((ext_vector_type(8))) short s16x8;
typedef __attribute__((ext_vector_type(4))) float f32x4;
typedef __attribute__((ext_vector_type(4))) u32   u32x4;
typedef __attribute__((ext_vector_type(4))) u16   u16x4;

#define NPIX 16641   /* 129*129 */
#define HP   131     /* padded spatial dim */

// ---- workspace layout (bytes) ----
// U    : [4][131][131][128] bf16  @ 0          (17,572,864)
// S1   : [2][131][131][512] bf16  @ 17572864   (35,145,728)
// Wt1  : [9][256][128] bf16       @ 52718592   (589,824)
// Wt2  : [9][256][512] bf16       @ 53308416   (2,359,296)
// out2a: [2*16641][256] bf16      @ 55667712   (17,040,384)  split-K half 0 (pre-relu, +bias)
// out2b: [2*16641][256] bf16      @ 72708096   (17,040,384)  split-K half 1
// w3t  : [256][49] f32            @ 89748480   (50,176)
// P    : [2][49][16641] f32       @ 89798656   (6,523,272)
// total 96,321,928 B

__device__ __forceinline__ u16 f2bf(float f) {
    u32 b = __builtin_bit_cast(u32, f);
    return (u16)((b + 0x7fffu + ((b >> 16) & 1u)) >> 16);
}
__device__ __forceinline__ float bf2f(u16 u) {
    return __builtin_bit_cast(float, ((u32)u) << 16);
}

// async global->LDS, 16B per lane; LDS dest wave-uniform base, lane l -> +16*l
__device__ __forceinline__ void async_cp16(const void* g, void* l) {
    __builtin_amdgcn_global_load_lds(
        (const __attribute__((address_space(1))) u32*)g,
        (__attribute__((address_space(3))) u32*)l, 16, 0, 0);
}

// zero only the 1-pixel pad ring of U (4 imgs, C=128) and S1 (2 imgs, C=512).
__global__ __launch_bounds__(256) void zero_border(u16* __restrict__ U,
                                                   u16* __restrict__ S1) {
    const int plane = blockIdx.y;           // 0..3: U, 4..5: S1
    const bool isU = plane < 4;
    const int C = isU ? 128 : 512;
    const int cpp = C / 8;
    int e = blockIdx.x * 256 + threadIdx.x;
    if (e >= 520 * cpp) return;
    int pix = e / cpp, ch = e - pix * cpp;
    int r, c;
    if (pix < 131)      { r = 0;   c = pix; }
    else if (pix < 262) { r = 130; c = pix - 131; }
    else { int j = pix - 262; r = 1 + (j >> 1); c = (j & 1) ? 130 : 0; }
    int img = isU ? plane : (plane - 4);
    u16* base = (isU ? U : S1) + ((long)(img * HP + r) * HP + c) * C + ch * 8;
    u32x4 z = {0u, 0u, 0u, 0u};
    *(u32x4*)base = z;
}

// transform weights: Wt[tap][co][ci] (bf16), w3t[c][t] (f32)
__global__ __launch_bounds__(256) void prep_weights(
        const float* __restrict__ wr, const float* __restrict__ w2,
        const float* __restrict__ w3,
        u16* __restrict__ Wt1, u16* __restrict__ Wt2, float* __restrict__ w3t) {
    int i = blockIdx.x * 256 + threadIdx.x;
    if (i < 294912) {
        int tap = i / 32768, r = i & 32767;
        int co = r >> 7, ci = r & 127;
        Wt1[i] = f2bf(wr[(co * 128 + ci) * 9 + tap]);
    } else if (i < 1474560) {
        int j = i - 294912;
        int tap = j / 131072, r = j & 131071;
        int co = r >> 9, ci = r & 511;
        Wt2[j] = f2bf(w2[(co * 512 + ci) * 9 + tap]);
    } else if (i < 1487104) {
        int j = i - 1474560;
        int c = j / 49, t = j - c * 49;
        w3t[j] = w3[t * 256 + c];
    }
}

// bilinear upsample 33x33 -> 129x129, write padded NHWC bf16
__global__ __launch_bounds__(256) void upsample(
        const float* __restrict__ cur, const float* __restrict__ key,
        u16* __restrict__ U) {
    __shared__ float rows[2][128][33];
    const int y = blockIdx.x;
    const int img = blockIdx.y;
    const int frame = img >> 1, bb = img & 1;
    const float* src = (frame ? key : cur) + (long)bb * 128 * 1089;
    const float scale = 33.0f / 129.0f;
    float syf = (y + 0.5f) * scale - 0.5f;
    int sy0 = (int)floorf(syf);
    float wy = syf - (float)sy0;
    int sy0c = sy0 < 0 ? 0 : sy0;
    int sy1c = (sy0 + 1 > 32) ? 32 : sy0 + 1;
    for (int e = threadIdx.x; e < 2 * 128 * 33; e += 256) {
        int rr = e / 4224;
        int rem = e - rr * 4224;
        int c = rem / 33, sx = rem - c * 33;
        rows[rr][c][sx] = src[((long)c * 33 + (rr ? sy1c : sy0c)) * 33 + sx];
    }
    __syncthreads();
    u16* dst = U + ((long)(img * HP + (y + 1)) * HP + 1) * 128;
    for (int e = threadIdx.x; e < 129 * 128; e += 256) {
        int x = e >> 7, c = e & 127;
        float sxf = (x + 0.5f) * scale - 0.5f;
        int sx0 = (int)floorf(sxf);
        float wx = sxf - (float)sx0;
        int sx0c = sx0 < 0 ? 0 : sx0;
        int sx1c = (sx0 + 1 > 32) ? 32 : sx0 + 1;
        float v0 = rows[0][c][sx0c] * (1.f - wx) + rows[0][c][sx1c] * wx;
        float v1 = rows[1][c][sx0c] * (1.f - wx) + rows[1][c][sx1c] * wx;
        dst[(long)x * 128 + c] = f2bf(v0 * (1.f - wy) + v1 * wy);
    }
}

// implicit-GEMM 3x3 conv via MFMA, 128x128 tile, BK=32 — exact r4 inner loop
// (2-buffer LDS, __syncthreads, global_load_lds, conflict-free k-chunk
// rotation; verified conflicts = 0). SPLIT=2 doubles the grid for TLP:
// each block runs half the K-steps and stores its bf16 partial (pre-relu,
// bias in half 0 only) into its own buffer; conv3 combines.
template<int CIN, int MODE, int NWORK, int SPLIT>
__global__ __launch_bounds__(256) void conv_mfma(
        const u16* __restrict__ In, const u16* __restrict__ Wt,
        const float* __restrict__ bias,
        u16* __restrict__ Out0, u16* __restrict__ Out1) {
    constexpr int KC  = CIN / 32;
    constexpr int NS  = 9 * KC;
    constexpr int NSH = NS / SPLIT;
    constexpr int PER = (NWORK + 7) / 8;
    __shared__ u16 As[2][128 * 32];
    __shared__ u16 Bs[2][128 * 32];

    const int id = blockIdx.x;
    const int work = (id & 7) * PER + (id >> 3);
    if (work >= NWORK) return;
    int w = work;
    const int m0 = (w & 1) * 128; w >>= 1;
    int half = 0;
    if (SPLIT == 2) { half = w & 1; w >>= 1; }
    const int xi  = w % 131;
    const int img = w / 131;
    const int p0  = xi * 128;

    const int t    = threadIdx.x;
    const int srow = t >> 2;
    // swizzled global k-chunk for this staging lane (conflict-free, r4)
    const int scol = ((((t & 3) - (srow >> 1)) & 3) * 8);
    long ub[2];
    #pragma unroll
    for (int is = 0; is < 2; ++is) {
        int p = p0 + srow + is * 64; if (p > NPIX - 1) p = NPIX - 1;
        int y = p / 129, x = p - y * 129;
        ub[is] = ((long)(img * HP + y) * HP + x) * CIN + scol;
    }
    const long wb0 = (long)(m0 + srow) * CIN + scol;

    const int lane = t & 63;
    const int wave = t >> 6;
    const int wm = wave & 1, wn = wave >> 1;
    const int lm = lane & 15, lq = lane >> 4;
    const int koff = (((lq + (lm >> 1)) & 3) * 8);

    auto stage = [&](int s, int buf) {
        const int tap = s / KC;
        const int kc  = (s - tap * KC) * 32;
        const int ky = tap / 3, kx = tap - ky * 3;
        const long toff = (long)(ky * HP + kx) * CIN + kc;
        const u16* WtT = Wt + (long)tap * 256 * CIN + kc;
        char* Aw = (char*)&As[buf][0] + wave * 1024;
        char* Bw = (char*)&Bs[buf][0] + wave * 1024;
        async_cp16(WtT + wb0,             Aw);
        async_cp16(WtT + wb0 + 64L * CIN, Aw + 4096);
        async_cp16(In + ub[0] + toff,     Bw);
        async_cp16(In + ub[1] + toff,     Bw + 4096);
    };

    f32x4 acc[4][4];
    f32x4 zero = {0.f, 0.f, 0.f, 0.f};
    #pragma unroll
    for (int mt = 0; mt < 4; ++mt)
        #pragma unroll
        for (int nt = 0; nt < 4; ++nt) acc[mt][nt] = zero;

    const int s0 = half * NSH;
    stage(s0, 0);
    #pragma unroll 2
    for (int i = 0; i < NSH; ++i) {
        const int buf = i & 1;
        __syncthreads();                  // buf staged; buf^1 free
        if (i + 1 < NSH) stage(s0 + i + 1, buf ^ 1);
        s16x8 fa[4], fb[4];
        #pragma unroll
        for (int mt = 0; mt < 4; ++mt)
            fa[mt] = *(const s16x8*)&As[buf][(wm * 64 + mt * 16 + lm) * 32 + koff];
        #pragma unroll
        for (int nt = 0; nt < 4; ++nt)
            fb[nt] = *(const s16x8*)&Bs[buf][(wn * 64 + nt * 16 + lm) * 32 + koff];
        #pragma unroll
        for (int mt = 0; mt < 4; ++mt)
            #pragma unroll
            for (int nt = 0; nt < 4; ++nt)
                acc[mt][nt] = __builtin_amdgcn_mfma_f32_16x16x32_bf16(
                    fa[mt], fb[nt], acc[mt][nt], 0, 0, 0);
    }

    u16* OutBf = half ? Out1 : Out0;
    #pragma unroll
    for (int nt = 0; nt < 4; ++nt) {
        int p = p0 + wn * 64 + nt * 16 + lm;
        if (p > NPIX - 1) continue;
        long obase;
        if (MODE == 0) {
            int y = p / 129, x = p - y * 129;
            int bb = img & 1, frame = img >> 1;
            obase = ((long)(bb * HP + (y + 1)) * HP + (x + 1)) * 512 + frame * 256;
        } else {
            obase = ((long)img * NPIX + p) * 256;
        }
        #pragma unroll
        for (int mt = 0; mt < 4; ++mt) {
            int co = m0 + wm * 64 + mt * 16 + lq * 4;
            f32x4 bv = *(const f32x4*)(bias + co);
            if (MODE == 0) {
                float v0 = fmaxf(acc[mt][nt][0] + bv[0], 0.f);
                float v1 = fmaxf(acc[mt][nt][1] + bv[1], 0.f);
                float v2 = fmaxf(acc[mt][nt][2] + bv[2], 0.f);
                float v3 = fmaxf(acc[mt][nt][3] + bv[3], 0.f);
                u16x4 o = { f2bf(v0), f2bf(v1), f2bf(v2), f2bf(v3) };
                *(u16x4*)(OutBf + obase + co) = o;
            } else {
                // pre-relu bf16 partial; bias only in half 0; relu at combine
                float bs = half ? 0.f : 1.f;
                u16x4 o = { f2bf(acc[mt][nt][0] + bs * bv[0]),
                            f2bf(acc[mt][nt][1] + bs * bv[1]),
                            f2bf(acc[mt][nt][2] + bs * bv[2]),
                            f2bf(acc[mt][nt][3] + bs * bv[3]) };
                *(u16x4*)(OutBf + obase + co) = o;
            }
        }
    }
}

// combine split-K halves (add, relu) + 1x1 conv (256->49) + softmax.
// 2 threads/pixel (128 ch each), LDS reduce.
__global__ __launch_bounds__(256) void conv3_softmax(
        const u16* __restrict__ Xa, const u16* __restrict__ Xb,
        const float* __restrict__ W3t, const float* __restrict__ b3,
        float* __restrict__ P) {
    __shared__ float red[128][50];
    const int t = threadIdx.x;
    const int pl = t & 127, sub = t >> 7;
    const int idx = blockIdx.x * 128 + pl;
    const bool valid = idx < 2 * NPIX;
    float l[49];
    #pragma unroll
    for (int k = 0; k < 49; ++k) l[k] = 0.f;
    if (valid) {
        const s16x8* xra = (const s16x8*)(Xa + (long)idx * 256 + sub * 128);
        const s16x8* xrb = (const s16x8*)(Xb + (long)idx * 256 + sub * 128);
        #pragma unroll 1
        for (int cb = 0; cb < 16; ++cb) {
            s16x8 av = xra[cb];
            s16x8 bv = xrb[cb];
            #pragma unroll
            for (int j = 0; j < 8; ++j) {
                float xc = fmaxf(bf2f((u16)av[j]) + bf2f((u16)bv[j]), 0.f);
                const float* wrow = W3t + (sub * 128 + cb * 8 + j) * 49;
                #pragma unroll
                for (int k = 0; k < 49; ++k) l[k] = fmaf(wrow[k], xc, l[k]);
            }
        }
    }
    if (sub) {
        #pragma unroll
        for (int k = 0; k < 49; ++k) red[pl][k] = l[k];
    }
    __syncthreads();
    if (!sub && valid) {
        float m = 0.f;
        #pragma unroll
        for (int k = 0; k < 49; ++k) {
            l[k] = fmaxf(l[k] + red[pl][k] + b3[k], 0.f);
            m = fmaxf(m, l[k]);
        }
        float ssum = 0.f;
        #pragma unroll
        for (int k = 0; k < 49; ++k) { l[k] = __expf(l[k] - m); ssum += l[k]; }
        float inv = 1.f / ssum;
        int bb = idx / NPIX, pix = idx - bb * NPIX;
        float* Pp = P + (long)bb * 49 * NPIX + pix;
        #pragma unroll
        for (int k = 0; k < 49; ++k) Pp[(long)k * NPIX] = l[k] * inv;
    }
}

// spatially-variant 7x7 conv
__global__ __launch_bounds__(256) void svconv(
        const float* __restrict__ F, const float* __restrict__ P,
        float* __restrict__ Out) {
    int idx = blockIdx.x * 256 + threadIdx.x;
    if (idx >= 2 * 64 * NPIX) return;
    int pix = idx % NPIX;
    int r = idx / NPIX;
    int cg = (r & 63), bb = r >> 6;
    int y = pix / 129, x = pix - y * 129;
    float w[49];
    const float* Pp = P + (long)bb * 49 * NPIX + pix;
    #pragma unroll
    for (int t = 0; t < 49; ++t) w[t] = Pp[(long)t * NPIX];
    float acc0 = 0.f, acc1 = 0.f, acc2 = 0.f, acc3 = 0.f;
    const float* Fb = F + ((long)(bb * 256 + cg * 4)) * NPIX;
    #pragma unroll
    for (int ky = 0; ky < 7; ++ky) {
        unsigned uy = (unsigned)(y + ky - 3);
        #pragma unroll
        for (int kx = 0; kx < 7; ++kx) {
            unsigned ux = (unsigned)(x + kx - 3);
            if (uy < 129u && ux < 129u) {
                long o = (long)uy * 129 + ux;
                float wt = w[ky * 7 + kx];
                acc0 = fmaf(wt, Fb[o], acc0);
                acc1 = fmaf(wt, Fb[o + (long)NPIX], acc1);
                acc2 = fmaf(wt, Fb[o + 2L * NPIX], acc2);
                acc3 = fmaf(wt, Fb[o + 3L * NPIX], acc3);
            }
        }
    }
    float* Ob = Out + ((long)(bb * 256 + cg * 4)) * NPIX + pix;
    Ob[0] = acc0;
    Ob[(long)NPIX] = acc1;
    Ob[2L * NPIX] = acc2;
    Ob[3L * NPIX] = acc3;
}

extern "C" void kernel_launch(void* const* d_in, const int* in_sizes, int n_in,
                              void* d_out, int out_size, void* d_ws, size_t ws_size,
                              hipStream_t stream) {
    const float* cur      = (const float*)d_in[0];
    const float* key      = (const float*)d_in[1];
    const float* Fhigh    = (const float*)d_in[2];
    const float* w_reduce = (const float*)d_in[3];
    const float* b_reduce = (const float*)d_in[4];
    const float* w_conv2  = (const float*)d_in[5];
    const float* b_conv2  = (const float*)d_in[6];
    const float* w_conv3  = (const float*)d_in[7];
    const float* b_conv3  = (const float*)d_in[8];

    if (ws_size < 96321928UL) return;

    char* ws = (char*)d_ws;
    u16*   U     = (u16*)(ws + 0);
    u16*   S1    = (u16*)(ws + 17572864);
    u16*   Wt1   = (u16*)(ws + 52718592);
    u16*   Wt2   = (u16*)(ws + 53308416);
    u16*   out2a = (u16*)(ws + 55667712);
    u16*   out2b = (u16*)(ws + 72708096);
    float* w3t   = (float*)(ws + 89748480);
    float* P     = (float*)(ws + 89798656);

    zero_border<<<dim3(130, 6), 256, 0, stream>>>(U, S1);
    prep_weights<<<5809, 256, 0, stream>>>(w_reduce, w_conv2, w_conv3, Wt1, Wt2, w3t);
    upsample<<<dim3(129, 4), 256, 0, stream>>>(cur, key, U);
    conv_mfma<128, 0, 1048, 1><<<1048, 256, 0, stream>>>(U, Wt1, b_reduce, S1, S1);
    conv_mfma<512, 1, 1048, 2><<<1048, 256, 0, stream>>>(S1, Wt2, b_conv2, out2a, out2b);
    conv3_softmax<<<261, 256, 0, stream>>>(out2a, out2b, w3t, b_conv3, P);
    svconv<<<8321, 256, 0, stream>>>(Fhigh, P, (float*)d_out);
}